// Round 2
// baseline (376.268 us; speedup 1.0000x reference)
//
#include <hip/hip_runtime.h>
#include <math.h>

// TopKRouter: x (16384 x 2048) @ gate_w^T (2048 x 64) -> top-2 + softmax.
// Output (f32): [indices as floats (N*2)] ++ [weights (N*2)].
//
// v2 design: lane = row (64 rows/wave). w is wave-uniform -> SGPR via
// readfirstlane'd expert offset (s_load path), FMAs are v_fmac v,s,v.
// x staged to LDS [64][64] with XOR swizzle byte^=(row&7)<<4 (conflict-free
// b128 read+write). 512 thr = 8 waves (2/SIMD), each wave owns 8 experts.
// Double-buffered LDS; global loads issued before compute (latency hidden).

constexpr int D_DIM = 2048;
constexpr int E_DIM = 64;
constexpr int BM    = 64;   // rows per block
constexpr int BK    = 64;   // k-chunk
constexpr int NC    = D_DIM / BK;  // 32 chunks

__global__ __launch_bounds__(512, 1)
void router_v2(const float* __restrict__ x,
               const float* __restrict__ w,
               float* __restrict__ out,
               int nrows) {
    __shared__ alignas(16) float xb[2][BM * BK];   // 2 x 16 KB
    __shared__ alignas(16) float lgs[BM * 65];     // logits, pad 65 (conflict-free scan)

    const int t    = threadIdx.x;
    const int lane = t & 63;            // row within tile
    const int wv   = t >> 6;            // wave id 0..7
    const int e0   = __builtin_amdgcn_readfirstlane(wv * 8);  // force SGPR
    const int row0 = blockIdx.x * BM;
    const float* __restrict__ wg = w + (size_t)e0 * D_DIM;    // uniform base

    // ---- staging helpers: 4096 floats/chunk = 1024 float4, 512 thr -> 2 each
    float4 va[2];
    auto g_load = [&](int c) {
        #pragma unroll
        for (int i = 0; i < 2; ++i) {
            const int id = t + i * 512;
            const int r  = id >> 4;      // 0..63
            const int kc = id & 15;      // float4 idx in row
            va[i] = *reinterpret_cast<const float4*>(
                x + (size_t)(row0 + r) * D_DIM + c * BK + kc * 4);
        }
    };
    auto lds_write = [&](int b) {
        #pragma unroll
        for (int i = 0; i < 2; ++i) {
            const int id = t + i * 512;
            const int r  = id >> 4;
            const int kc = id & 15;
            char* p = (char*)xb[b] + r * 256 + ((kc * 16) ^ ((r & 7) << 4));
            *reinterpret_cast<float4*>(p) = va[i];
        }
    };

    float acc[8] = {};
    auto compute = [&](int b, int c) {
        const char* base = (const char*)xb[b] + lane * 256;
        const int   sw   = (lane & 7) << 4;
        #pragma unroll
        for (int j8 = 0; j8 < 8; ++j8) {     // 8 k-values per iter
            const float4 xa = *reinterpret_cast<const float4*>(base + ((j8 * 32) ^ sw));
            const float4 xc = *reinterpret_cast<const float4*>(base + ((j8 * 32 + 16) ^ sw));
            const float* wp0 = wg + c * BK + j8 * 8;   // uniform -> s_load
            #pragma unroll
            for (int e = 0; e < 8; ++e) {
                const float* wp = wp0 + (size_t)e * D_DIM;
                acc[e] += xa.x * wp[0] + xa.y * wp[1] + xa.z * wp[2] + xa.w * wp[3]
                        + xc.x * wp[4] + xc.y * wp[5] + xc.z * wp[6] + xc.w * wp[7];
            }
        }
    };

    // ---- pipelined main loop ----
    g_load(0);
    lds_write(0);
    __syncthreads();
    for (int c = 0; c < NC; ++c) {
        if (c + 1 < NC) g_load(c + 1);        // issue global loads early
        compute(c & 1, c);                    // 512 FMA/thread under the loads
        __syncthreads();                      // everyone done reading buf[(c+1)&1]
        if (c + 1 < NC) lds_write((c + 1) & 1);
        __syncthreads();                      // writes visible
    }

    // ---- epilogue: logits -> LDS, per-row top-2 + softmax ----
    #pragma unroll
    for (int e = 0; e < 8; ++e)
        lgs[lane * 65 + e0 + e] = acc[e];
    __syncthreads();

    if (t < BM) {
        const float* lg = &lgs[t * 65];
        float m1 = lg[0]; int i1 = 0;
        float m2 = -INFINITY; int i2 = 0;
        #pragma unroll
        for (int e = 1; e < E_DIM; ++e) {
            const float v = lg[e];
            if (v > m1)      { m2 = m1; i2 = i1; m1 = v; i1 = e; }
            else if (v > m2) { m2 = v;  i2 = e; }
        }
        const float e2 = expf(m2 - m1);
        const float s  = 1.0f + e2;
        const long  r  = row0 + t;
        const long  off = (long)nrows * 2;
        out[2 * r + 0]       = (float)i1;
        out[2 * r + 1]       = (float)i2;
        out[off + 2 * r + 0] = 1.0f / s;
        out[off + 2 * r + 1] = e2 / s;
    }
}

extern "C" void kernel_launch(void* const* d_in, const int* in_sizes, int n_in,
                              void* d_out, int out_size, void* d_ws, size_t ws_size,
                              hipStream_t stream) {
    const float* x = (const float*)d_in[0];
    const float* w = (const float*)d_in[1];
    float* out = (float*)d_out;
    const int nrows = in_sizes[0] / D_DIM;   // 16384
    const int grid  = nrows / BM;            // 256
    hipLaunchKernelGGL(router_v2, dim3(grid), dim3(512), 0, stream,
                       x, w, out, nrows);
}

// Round 3
// 55.165 us; speedup vs baseline: 6.8207x; 6.8207x over previous
//
#include <hip/hip_runtime.h>
#include <hip/hip_bf16.h>
#include <math.h>

// TopKRouter: x (16384 x 2048) f32 @ gate_w^T (2048 x 64) -> top-2 + softmax.
// Output (f32): [indices as floats (N*2)] ++ [weights (N*2)].
//
// v3: split-bf16 MFMA (Ootomo). v = hi + lo (both bf16); logits =
// ah*bh + ah*bl + al*bh via 3 chained mfma_f32_16x16x32_bf16 -> err ~1e-6.
// w pre-split/packed into d_ws by a tiny pre-kernel. Main loop: barrier-free,
// A-frags straight from global (coalesced 128B/row per wave), B-frags from
// packed w (L2-resident). 4 waves/block split K over the same 32 rows;
// LDS reduce + shfl top-2 epilogue.

constexpr int D_DIM  = 2048;
constexpr int E_DIM  = 64;
constexpr int BROWS  = 32;              // rows per block (all 4 waves)
constexpr int KSLICE = D_DIM / 4;       // 512 per wave
constexpr int KSTEPS = KSLICE / 32;     // 16
constexpr int LPAD   = 68;              // logits LDS row stride (f32)

typedef __attribute__((ext_vector_type(8))) short s16x8;  // 8 bf16 (MFMA A/B)
typedef __attribute__((ext_vector_type(4))) float f32x4;  // MFMA C/D

static __device__ __forceinline__ short f2bf(float f) {
    __hip_bfloat16 h = __float2bfloat16(f);   // RNE
    return *reinterpret_cast<short*>(&h);
}
static __device__ __forceinline__ float b2f(short s) {
    union { unsigned u; float f; } x;
    x.u = ((unsigned)(unsigned short)s) << 16;
    return x.f;
}

__global__ __launch_bounds__(256, 1)
void pack_w(const float* __restrict__ w, short* __restrict__ wsb) {
    const int idx = blockIdx.x * 256 + threadIdx.x;   // 64*2048 total
    const int e = idx >> 11, k = idx & 2047;
    const float v = w[idx];
    const short hi = f2bf(v);
    const short lo = f2bf(v - b2f(hi));
    const int g = k >> 3, j = k & 7;
    // layout: [e][g][s][j], s=0 hi, s=1 lo -> frag-ready 16B groups
    const size_t base = ((size_t)(e * 256 + g) * 2) * 8 + j;
    wsb[base]     = hi;
    wsb[base + 8] = lo;
}

template <bool PACKED>
__global__ __launch_bounds__(256, 2)
void router_mfma(const float* __restrict__ x,
                 const float* __restrict__ w,
                 const short* __restrict__ wsb,
                 float* __restrict__ out,
                 int nrows) {
    __shared__ alignas(16) float lgs[4][BROWS][LPAD];   // 34.8 KB

    const int t    = threadIdx.x;
    const int lane = t & 63;
    const int wv   = t >> 6;            // wave id -> K-slice
    const int row0 = blockIdx.x * BROWS;
    const int l15  = lane & 15;
    const int k8   = lane >> 4;         // which 8-k group within K=32
    const int k0   = wv * KSLICE;

    f32x4 acc[2][4];
    const f32x4 zero = {0.f, 0.f, 0.f, 0.f};
    #pragma unroll
    for (int mf = 0; mf < 2; ++mf)
        #pragma unroll
        for (int nf = 0; nf < 4; ++nf) acc[mf][nf] = zero;

    #pragma unroll 2
    for (int i = 0; i < KSTEPS; ++i) {
        const int kk = k0 + i * 32 + k8 * 8;
        // ---- A fragments: 2 row-groups x 8 f32 -> split hi/lo bf16 ----
        s16x8 ah[2], al[2];
        #pragma unroll
        for (int mf = 0; mf < 2; ++mf) {
            const float* px = x + (size_t)(row0 + mf * 16 + l15) * D_DIM + kk;
            const float4 v0 = *reinterpret_cast<const float4*>(px);
            const float4 v1 = *reinterpret_cast<const float4*>(px + 4);
            const float vv[8] = {v0.x, v0.y, v0.z, v0.w, v1.x, v1.y, v1.z, v1.w};
            #pragma unroll
            for (int j = 0; j < 8; ++j) {
                const short h = f2bf(vv[j]);
                ah[mf][j] = h;
                al[mf][j] = f2bf(vv[j] - b2f(h));
            }
        }
        // ---- B fragments: 4 expert-groups, hi/lo ----
        s16x8 bh[4], bl[4];
        #pragma unroll
        for (int nf = 0; nf < 4; ++nf) {
            const int e = nf * 16 + l15;
            if (PACKED) {
                const int g = (k0 >> 3) + i * 4 + k8;
                const short* pw = wsb + (size_t)(e * 256 + g) * 16;
                bh[nf] = *reinterpret_cast<const s16x8*>(pw);
                bl[nf] = *reinterpret_cast<const s16x8*>(pw + 8);
            } else {
                const float* pw = w + (size_t)e * D_DIM + kk;
                const float4 w0 = *reinterpret_cast<const float4*>(pw);
                const float4 w1 = *reinterpret_cast<const float4*>(pw + 4);
                const float wvv[8] = {w0.x, w0.y, w0.z, w0.w, w1.x, w1.y, w1.z, w1.w};
                #pragma unroll
                for (int j = 0; j < 8; ++j) {
                    const short h = f2bf(wvv[j]);
                    bh[nf][j] = h;
                    bl[nf][j] = f2bf(wvv[j] - b2f(h));
                }
            }
        }
        // ---- 3-term split MFMA ----
        #pragma unroll
        for (int mf = 0; mf < 2; ++mf)
            #pragma unroll
            for (int nf = 0; nf < 4; ++nf) {
                acc[mf][nf] = __builtin_amdgcn_mfma_f32_16x16x32_bf16(al[mf], bh[nf], acc[mf][nf], 0, 0, 0);
                acc[mf][nf] = __builtin_amdgcn_mfma_f32_16x16x32_bf16(ah[mf], bl[nf], acc[mf][nf], 0, 0, 0);
                acc[mf][nf] = __builtin_amdgcn_mfma_f32_16x16x32_bf16(ah[mf], bh[nf], acc[mf][nf], 0, 0, 0);
            }
    }

    // ---- partials -> LDS. C/D layout: col = lane&15, row = (lane>>4)*4+reg ----
    #pragma unroll
    for (int mf = 0; mf < 2; ++mf)
        #pragma unroll
        for (int nf = 0; nf < 4; ++nf)
            #pragma unroll
            for (int j = 0; j < 4; ++j)
                lgs[wv][mf * 16 + k8 * 4 + j][nf * 16 + l15] = acc[mf][nf][j];
    __syncthreads();

    // ---- reduce 4 K-partials + per-row top-2 + softmax ----
    // wave wv handles rows [wv*8, wv*8+8); lane: row8 = lane>>3, seg = lane&7
    {
        const int row8 = lane >> 3;
        const int seg  = lane & 7;
        const int row  = wv * 8 + row8;
        float s[8];
        #pragma unroll
        for (int j = 0; j < 8; ++j) s[j] = 0.f;
        #pragma unroll
        for (int p = 0; p < 4; ++p) {
            const float4 a = *reinterpret_cast<const float4*>(&lgs[p][row][seg * 8]);
            const float4 b = *reinterpret_cast<const float4*>(&lgs[p][row][seg * 8 + 4]);
            s[0] += a.x; s[1] += a.y; s[2] += a.z; s[3] += a.w;
            s[4] += b.x; s[5] += b.y; s[6] += b.z; s[7] += b.w;
        }
        float m1 = s[0]; int i1 = seg * 8;
        float m2 = -INFINITY; int i2 = 0;
        #pragma unroll
        for (int j = 1; j < 8; ++j) {
            const float v = s[j]; const int idx = seg * 8 + j;
            if (v > m1)      { m2 = m1; i2 = i1; m1 = v; i1 = idx; }
            else if (v > m2) { m2 = v;  i2 = idx; }
        }
        // merge across the 8 segs (lanes differing in bits 0..2)
        #pragma unroll
        for (int d = 1; d < 8; d <<= 1) {
            const float M1 = __shfl_xor(m1, d); const int I1 = __shfl_xor(i1, d);
            const float M2 = __shfl_xor(m2, d); const int I2 = __shfl_xor(i2, d);
            const bool sw = (M1 > m1) || (M1 == m1 && I1 < i1);
            const float a1 = sw ? M1 : m1; const int j1 = sw ? I1 : i1;
            const float b1 = sw ? m1 : M1; const int kx = sw ? i1 : I1;
            const float a2 = sw ? M2 : m2; const int j2 = sw ? I2 : i2;
            const bool t2 = (b1 > a2) || (b1 == a2 && kx < j2);
            m1 = a1; i1 = j1;
            m2 = t2 ? b1 : a2; i2 = t2 ? kx : j2;
        }
        if (seg == 0) {
            const float e2v = expf(m2 - m1);
            const float sm  = 1.0f + e2v;
            const long  r   = row0 + row;
            const long  off = (long)nrows * 2;
            out[2 * r + 0]       = (float)i1;
            out[2 * r + 1]       = (float)i2;
            out[off + 2 * r + 0] = 1.0f / sm;
            out[off + 2 * r + 1] = e2v / sm;
        }
    }
}

extern "C" void kernel_launch(void* const* d_in, const int* in_sizes, int n_in,
                              void* d_out, int out_size, void* d_ws, size_t ws_size,
                              hipStream_t stream) {
    const float* x = (const float*)d_in[0];
    const float* w = (const float*)d_in[1];
    float* out = (float*)d_out;
    short* wsb = (short*)d_ws;
    const int nrows = in_sizes[0] / D_DIM;            // 16384
    const int grid  = nrows / BROWS;                  // 512
    const bool packed = ws_size >= (size_t)(E_DIM * D_DIM * 2 * sizeof(short));

    if (packed) {
        hipLaunchKernelGGL(pack_w, dim3(E_DIM * D_DIM / 256), dim3(256), 0, stream, w, wsb);
        hipLaunchKernelGGL(router_mfma<true>, dim3(grid), dim3(256), 0, stream,
                           x, w, wsb, out, nrows);
    } else {
        hipLaunchKernelGGL(router_mfma<false>, dim3(grid), dim3(256), 0, stream,
                           x, w, wsb, out, nrows);
    }
}